// Round 2
// baseline (206.103 us; speedup 1.0000x reference)
//
#include <hip/hip_runtime.h>

#define NTAG 32
#define START 30
#define STOP 31
#define LOG2E 1.44269504088896340736f
#define LN2 0.69314718055994530942f

typedef float f4 __attribute__((ext_vector_type(4)));

__device__ __forceinline__ float fexp2(float x) {
#if __has_builtin(__builtin_amdgcn_exp2f)
    return __builtin_amdgcn_exp2f(x);   // v_exp_f32: 2^x
#else
    return exp2f(x);
#endif
}
__device__ __forceinline__ float flog2(float x) {
#if __has_builtin(__builtin_amdgcn_logf)
    return __builtin_amdgcn_logf(x);    // v_log_f32: log2(x)
#else
    return log2f(x);
#endif
}

#define REPEAT32(M) \
    M(0) M(1) M(2) M(3) M(4) M(5) M(6) M(7) \
    M(8) M(9) M(10) M(11) M(12) M(13) M(14) M(15) \
    M(16) M(17) M(18) M(19) M(20) M(21) M(22) M(23) \
    M(24) M(25) M(26) M(27) M(28) M(29) M(30) M(31)

// One quad of the matvec: su values come from an LDS broadcast quad (VGPRs),
// accumulator assignment (i & 3) and i-ascending order match the previous
// kernel bitwise.
#define QUAD_FMA(q, i0, i1, i2, i3) \
    a0_ = fmaf((q).x, ET2_##i0, a0_); \
    a1_ = fmaf((q).y, ET2_##i1, a1_); \
    a2_ = fmaf((q).z, ET2_##i2, a2_); \
    a3_ = fmaf((q).w, ET2_##i3, a3_);

// One LINEAR-domain scan step.  Broadcast of S is LDS write + 8x
// uniform-address ds_read_b128 (per 32-lane half) -> all-VGPR dataflow on
// the serial chain (no v_readlane/SGPR path).  Same-wave DS ops are
// processed in order by the LDS pipe, so no barrier is required.
// RN: exact pow2 renorm, k taken from the broadcast old S[0] (q0.x) ->
// VALU-only, no readfirstlane/SALU round trip.  Snapshot (Sfin/M2f) at
// tt == n-1 is off the critical chain.
#define STEP_CORE(fraw_, tt_, RN) { \
    const float F_ = fexp2((fraw_) * LOG2E); \
    *swr = S; \
    const f4 q0 = srd[0]; const f4 q1 = srd[1]; \
    const f4 q2 = srd[2]; const f4 q3 = srd[3]; \
    const f4 q4 = srd[4]; const f4 q5 = srd[5]; \
    const f4 q6 = srd[6]; const f4 q7 = srd[7]; \
    float a0_ = 0.f, a1_ = 0.f, a2_ = 0.f, a3_ = 0.f; \
    QUAD_FMA(q0, 0, 1, 2, 3)     QUAD_FMA(q1, 4, 5, 6, 7) \
    QUAD_FMA(q2, 8, 9, 10, 11)   QUAD_FMA(q3, 12, 13, 14, 15) \
    QUAD_FMA(q4, 16, 17, 18, 19) QUAD_FMA(q5, 20, 21, 22, 23) \
    QUAD_FMA(q6, 24, 25, 26, 27) QUAD_FMA(q7, 28, 29, 30, 31) \
    S = ((a0_ + a1_) + (a2_ + a3_)) * F_; \
    if (RN) { \
        const int k_ = ((__float_as_int(q0.x) >> 23) & 0xff) - 127; \
        S = __int_as_float(__float_as_int(S) - (k_ << 23)); \
        M2i += k_; \
    } \
    { const bool cap_ = ((tt_) == nm1); \
      Sfin = cap_ ? S : Sfin; \
      M2f  = cap_ ? M2i : M2f; } }

// Consume slot FS (feat for step tt_) and immediately reload it with time
// index tload (16 steps ahead) -> consume always waits on a ~16-step-old load.
#define STEP_RELOAD(FS, tt_, tload, RN) { \
    const float fraw_ = FS; \
    { const int tc_ = ((tload) < L - 1) ? (tload) : (L - 1); \
      FS = frow[tc_ * NTAG + j]; } \
    STEP_CORE(fraw_, tt_, RN) }

#define STEP_NORELOAD(FS, tt_, RN) { const float fraw_ = FS; STEP_CORE(fraw_, tt_, RN) }

// Block = 256 threads = 4 waves.  Waves 0-1: serial alpha scans, TWO batches
// per wave (lanes 0-31 = batch A tags, lanes 32-63 = batch B tags; broadcast
// is per-half via LDS).  Waves 2-3: gold-score gathers (2 batches each).
// Grid = B/4 = 256 blocks = 1 block/CU -> 2 scan waves/CU sharing the LDS pipe.
__global__ __launch_bounds__(256, 2) void crf_nll_kernel(
    const float* __restrict__ feats,   // B x L x 32
    const float* __restrict__ trans,   // 32 x 32
    const int*   __restrict__ tags,    // B x L
    const int*   __restrict__ wsl,     // B
    float* __restrict__ out, int B, int L)
{
    __shared__ float strans[NTAG * NTAG];
    __shared__ __align__(16) float sS[2][2][NTAG];   // [scan wave][half][tag]
    for (int i = threadIdx.x; i < NTAG * NTAG; i += 256) strans[i] = trans[i];
    __syncthreads();

    const int wave = threadIdx.x >> 6;
    const int lane = threadIdx.x & 63;

    if (wave < 2) {
        // ================= scan waves (2 batches per wave) =================
        const int half = lane >> 5;
        const int j = lane & 31;
        int b = blockIdx.x * 4 + wave * 2 + half;
        const int bok = (b < B);
        if (!bok) b = B - 1;

        // linear transition matrix column j: ET2_i = 2^(trans[i][j]*log2e)
#define DECL_ET2(i) float ET2_##i = fexp2(strans[(i) * NTAG + j] * LOG2E);
        REPEAT32(DECL_ET2)
#undef DECL_ET2
        const float tS2 = strans[j * NTAG + STOP] * LOG2E;

        const int n = wsl[b];            // per-half (uniform within half)
        const int nm1 = n - 1;
        int nmax;
        { const int o = __shfl_xor(n, 32, 64); nmax = n > o ? n : o; }
        nmax = __builtin_amdgcn_readfirstlane(nmax);

        const float* __restrict__ frow = feats + (size_t)b * L * NTAG;

        // init (t = 0): S_j = 2^((trans[START][j]+feat0_j)*log2e), M2i = 0
        // invariant: alpha_j(t) = ln2 * (M2i + log2 S_j)
        float S = fexp2((strans[START * NTAG + j] + frow[j]) * LOG2E);
        int M2i = 0;
        float Sfin = S;                  // snapshot at t == n-1 (covers n==1)
        int M2f = 0;

        float* const swr = &sS[wave][half][j];                 // per-lane write slot
        const f4* const srd = (const f4*)&sS[wave][half][0];   // per-half broadcast base

        // two prefetch groups of 8 named slots; invariant at loop head:
        //   fA_i = feat(t + i),  fB_i = feat(t + 8 + i)
#define LDF(t_) frow[(((t_) < L - 1) ? (t_) : (L - 1)) * NTAG + j]
        float fA0 = LDF(1),  fA1 = LDF(2),  fA2 = LDF(3),  fA3 = LDF(4),
              fA4 = LDF(5),  fA5 = LDF(6),  fA6 = LDF(7),  fA7 = LDF(8);
        float fB0 = LDF(9),  fB1 = LDF(10), fB2 = LDF(11), fB3 = LDF(12),
              fB4 = LDF(13), fB5 = LDF(14), fB6 = LDF(15), fB7 = LDF(16);
#undef LDF

        int t = 1;
        for (; t + 16 <= nmax; t += 16) {
            // pin ET2 in VGPRs (zero-instruction insurance against remat/spill)
            asm volatile("" : "+v"(ET2_0),  "+v"(ET2_1),  "+v"(ET2_2),  "+v"(ET2_3),
                              "+v"(ET2_4),  "+v"(ET2_5),  "+v"(ET2_6),  "+v"(ET2_7));
            asm volatile("" : "+v"(ET2_8),  "+v"(ET2_9),  "+v"(ET2_10), "+v"(ET2_11),
                              "+v"(ET2_12), "+v"(ET2_13), "+v"(ET2_14), "+v"(ET2_15));
            asm volatile("" : "+v"(ET2_16), "+v"(ET2_17), "+v"(ET2_18), "+v"(ET2_19),
                              "+v"(ET2_20), "+v"(ET2_21), "+v"(ET2_22), "+v"(ET2_23));
            asm volatile("" : "+v"(ET2_24), "+v"(ET2_25), "+v"(ET2_26), "+v"(ET2_27),
                              "+v"(ET2_28), "+v"(ET2_29), "+v"(ET2_30), "+v"(ET2_31));
            // steps t .. t+7 consume group A, reload A <- t+16 .. t+23
            STEP_RELOAD(fA0, t + 0,  t + 16, 0)
            STEP_RELOAD(fA1, t + 1,  t + 17, 0)
            STEP_RELOAD(fA2, t + 2,  t + 18, 0)
            STEP_RELOAD(fA3, t + 3,  t + 19, 1)   // exact pow2 renorm every 4 steps
            STEP_RELOAD(fA4, t + 4,  t + 20, 0)
            STEP_RELOAD(fA5, t + 5,  t + 21, 0)
            STEP_RELOAD(fA6, t + 6,  t + 22, 0)
            STEP_RELOAD(fA7, t + 7,  t + 23, 1)
            // steps t+8 .. t+15 consume group B, reload B <- t+24 .. t+31
            STEP_RELOAD(fB0, t + 8,  t + 24, 0)
            STEP_RELOAD(fB1, t + 9,  t + 25, 0)
            STEP_RELOAD(fB2, t + 10, t + 26, 0)
            STEP_RELOAD(fB3, t + 11, t + 27, 1)
            STEP_RELOAD(fB4, t + 12, t + 28, 0)
            STEP_RELOAD(fB5, t + 13, t + 29, 0)
            STEP_RELOAD(fB6, t + 14, t + 30, 0)
            STEP_RELOAD(fB7, t + 15, t + 31, 1)
        }
        // epilogue: remaining nmax-t in [0,16); A holds t..t+7, B holds t+8..t+15
        if (t + 0  < nmax) { STEP_NORELOAD(fA0, t + 0,  1) }
        if (t + 1  < nmax) { STEP_NORELOAD(fA1, t + 1,  1) }
        if (t + 2  < nmax) { STEP_NORELOAD(fA2, t + 2,  1) }
        if (t + 3  < nmax) { STEP_NORELOAD(fA3, t + 3,  1) }
        if (t + 4  < nmax) { STEP_NORELOAD(fA4, t + 4,  1) }
        if (t + 5  < nmax) { STEP_NORELOAD(fA5, t + 5,  1) }
        if (t + 6  < nmax) { STEP_NORELOAD(fA6, t + 6,  1) }
        if (t + 7  < nmax) { STEP_NORELOAD(fA7, t + 7,  1) }
        if (t + 8  < nmax) { STEP_NORELOAD(fB0, t + 8,  1) }
        if (t + 9  < nmax) { STEP_NORELOAD(fB1, t + 9,  1) }
        if (t + 10 < nmax) { STEP_NORELOAD(fB2, t + 10, 1) }
        if (t + 11 < nmax) { STEP_NORELOAD(fB3, t + 11, 1) }
        if (t + 12 < nmax) { STEP_NORELOAD(fB4, t + 12, 1) }
        if (t + 13 < nmax) { STEP_NORELOAD(fB5, t + 13, 1) }
        if (t + 14 < nmax) { STEP_NORELOAD(fB6, t + 14, 1) }

        // forward score: ln2 * (M2f + log2 sum_j Sfin_j * 2^(trans[j,STOP]*log2e))
        float ex = Sfin * fexp2(tS2);
#pragma unroll
        for (int k = 1; k < 32; k <<= 1) ex += __shfl_xor(ex, k, 32);  // per-half reduce
        if (j == 0 && bok) atomicAdd(out, LN2 * ((float)M2f + flog2(ex)));
    } else {
        // ================= gold waves (pure gathers, 2 batches each) =========
        const int gw = wave - 2;
        for (int bb = 0; bb < 2; ++bb) {
            const int b = blockIdx.x * 4 + gw * 2 + bb;
            if (b >= B) break;
            const int n = wsl[b];
            const float* __restrict__ frow = feats + (size_t)b * L * NTAG;
            const int*   __restrict__ trow = tags  + (size_t)b * L;

            float acc = 0.f;
            for (int tt = lane; tt < L; tt += 64) {
                const int tg = trow[tt];
                if (tt == 0) {
                    acc += strans[START * NTAG + tg] + frow[tg];
                } else if (tt < n) {
                    const int tgp = trow[tt - 1];
                    acc += strans[tgp * NTAG + tg] + frow[tt * NTAG + tg];
                }
                if (tt == n - 1) {
                    acc += strans[tg * NTAG + STOP];
                }
            }
#pragma unroll
            for (int k = 1; k < 64; k <<= 1) acc += __shfl_xor(acc, k, 64);
            if (lane == 0) atomicAdd(out, -acc);
        }
    }
}

extern "C" void kernel_launch(void* const* d_in, const int* in_sizes, int n_in,
                              void* d_out, int out_size, void* d_ws, size_t ws_size,
                              hipStream_t stream) {
    const float* feats = (const float*)d_in[0];
    const float* trans = (const float*)d_in[1];
    const int*   tags  = (const int*)d_in[2];
    const int*   wsl   = (const int*)d_in[3];
    float* out = (float*)d_out;

    const int B = in_sizes[3];              // word_seq_lens: (B,)
    const int L = in_sizes[2] / B;          // tags: (B, L)

    (void)hipMemsetAsync(out, 0, sizeof(float), stream);
    const int grid = (B + 3) / 4;
    crf_nll_kernel<<<grid, 256, 0, stream>>>(feats, trans, tags, wsl, out, B, L);
}

// Round 3
// 190.258 us; speedup vs baseline: 1.0833x; 1.0833x over previous
//
#include <hip/hip_runtime.h>

#define NTAG 32
#define START 30
#define STOP 31
#define LOG2E 1.44269504088896340736f
#define LN2 0.69314718055994530942f

__device__ __forceinline__ float fexp2(float x) {
#if __has_builtin(__builtin_amdgcn_exp2f)
    return __builtin_amdgcn_exp2f(x);   // v_exp_f32: 2^x
#else
    return exp2f(x);
#endif
}
__device__ __forceinline__ float flog2(float x) {
#if __has_builtin(__builtin_amdgcn_logf)
    return __builtin_amdgcn_logf(x);    // v_log_f32: log2(x)
#else
    return log2f(x);
#endif
}

// DPP ROW_ROR control = 0x120 + r (rotate within 16-lane row; 4 batch groups
// of 16 lanes never mix).  Used on an int at init to DISCOVER the hardware
// rotation direction, so Erot is correct regardless of ror semantics.
#define DPP_ROR_I(x, R) __builtin_amdgcn_update_dpp(0, (x), 0x120 + (R), 0xf, 0xf, false)

#define REPEAT15(M) \
    M(1) M(2) M(3) M(4) M(5) M(6) M(7) M(8) \
    M(9) M(10) M(11) M(12) M(13) M(14) M(15)

// Pre-rotated linear transition values, matched to the hw rotation map:
//   rotation r delivers S from local lane q = rormap(p, r); pair it with
//   E2[q + 16*src_half][p + 16*dst_half].
#define DECL_E(r) \
    const int q##r = DPP_ROR_I(p, r); \
    float E##r##_00 = fexp2(strans[(q##r) * NTAG + p] * LOG2E); \
    float E##r##_01 = fexp2(strans[(q##r) * NTAG + p + 16] * LOG2E); \
    float E##r##_10 = fexp2(strans[(q##r + 16) * NTAG + p] * LOG2E); \
    float E##r##_11 = fexp2(strans[(q##r + 16) * NTAG + p + 16] * LOG2E);

// One rotation group: 4 single-instruction VOP2 fmacs with DPP on the S
// operand.  All-VGPR, in-pipe cross-lane: no SGPR writes, no DS pipe.
#define ROT4(r) \
    asm volatile("v_fmac_f32 %0, %1, %2 row_ror:" #r : "+v"(aL0) : "v"(S_lo), "v"(E##r##_00)); \
    asm volatile("v_fmac_f32 %0, %1, %2 row_ror:" #r : "+v"(aH0) : "v"(S_lo), "v"(E##r##_01)); \
    asm volatile("v_fmac_f32 %0, %1, %2 row_ror:" #r : "+v"(aL1) : "v"(S_hi), "v"(E##r##_10)); \
    asm volatile("v_fmac_f32 %0, %1, %2 row_ror:" #r : "+v"(aH1) : "v"(S_hi), "v"(E##r##_11));

// One LINEAR-domain scan step for the lane's batch group.
// invariant: alpha_j(t) = ln2 * (M2i + log2 S_j), S split lane-wise as
// S_lo = S[p], S_hi = S[p+16].
// RN: exact pow2 renorm; k from group-max exponent via DPP rotate-max
// (uniform within the 16-lane group).  s_nop 1 guards the
// VALU-write -> DPP-read wait-state hazard.
#define STEP_CORE(fLo_, fHi_, tt_, RN) { \
    const float FL_ = fexp2((fLo_) * LOG2E); \
    const float FH_ = fexp2((fHi_) * LOG2E); \
    float aL0 = S_lo * E0_00; \
    float aH0 = S_lo * E0_01; \
    float aL1 = S_hi * E0_10; \
    float aH1 = S_hi * E0_11; \
    asm volatile("s_nop 1");  /* S_{lo,hi} written at prior step end */ \
    REPEAT15(ROT4) \
    S_lo = (aL0 + aL1) * FL_; \
    S_hi = (aH0 + aH1) * FH_; \
    if (RN) { \
        float m_ = fmaxf(S_lo, S_hi); \
        asm volatile("s_nop 1\n\t" \
            "v_max_f32 %0, %0, %0 row_ror:1\n\ts_nop 1\n\t" \
            "v_max_f32 %0, %0, %0 row_ror:2\n\ts_nop 1\n\t" \
            "v_max_f32 %0, %0, %0 row_ror:4\n\ts_nop 1\n\t" \
            "v_max_f32 %0, %0, %0 row_ror:8" : "+v"(m_)); \
        const int ke_ = ((__float_as_int(m_) >> 23) & 0xff) - 127; \
        S_lo = __int_as_float(__float_as_int(S_lo) - (ke_ << 23)); \
        S_hi = __int_as_float(__float_as_int(S_hi) - (ke_ << 23)); \
        M2i += ke_; \
    } \
    { const bool cap_ = ((tt_) == nm1); \
      SfL = cap_ ? S_lo : SfL; \
      SfH = cap_ ? S_hi : SfH; \
      M2f = cap_ ? M2i : M2f; } }

// Consume slots (feat pair for step tt_) and immediately reload them with
// time index tload (8 steps ahead) -> consume waits on an 8-step-old load.
#define STEP_RELOAD(FL, FH, tt_, tload, RN) { \
    const float fl_ = FL, fh_ = FH; \
    { const int tc_ = ((tload) < L - 1) ? (tload) : (L - 1); \
      const float* ap_ = frow + tc_ * NTAG + p; \
      FL = ap_[0]; FH = ap_[16]; } \
    STEP_CORE(fl_, fh_, tt_, RN) }

#define STEP_NORELOAD(FL, FH, tt_, RN) { const float fl_ = FL, fh_ = FH; STEP_CORE(fl_, fh_, tt_, RN) }

// Block = 256 threads = 4 waves.  Wave 0: serial alpha scans for FOUR batches
// (lanes = 4 groups of 16; lane p of group g holds tags p and p+16 of batch
// blockIdx*4+g).  Cross-lane matvec gather = DPP row rotations (in-pipe).
// Waves 1-3: gold-score gathers.  Grid = B/4 = 256 blocks = 1 block/CU.
__global__ __launch_bounds__(256, 1) void crf_nll_kernel(
    const float* __restrict__ feats,   // B x L x 32
    const float* __restrict__ trans,   // 32 x 32
    const int*   __restrict__ tags,    // B x L
    const int*   __restrict__ wsl,     // B
    float* __restrict__ out, int B, int L)
{
    __shared__ float strans[NTAG * NTAG];
    for (int i = threadIdx.x; i < NTAG * NTAG; i += 256) strans[i] = trans[i];
    __syncthreads();

    const int wave = threadIdx.x >> 6;
    const int lane = threadIdx.x & 63;

    if (wave == 0) {
        // ================= scan wave (4 batches, 16 lanes each) =============
        const int g = lane >> 4;          // batch group
        const int p = lane & 15;          // local tag lane: owns tags p, p+16
        int b = blockIdx.x * 4 + g;
        const int bok = (b < B);
        if (!bok) b = B - 1;

        // rotation-matched linear transition registers (64 regs)
        const int q0 = p;
        float E0_00 = fexp2(strans[q0 * NTAG + p] * LOG2E);
        float E0_01 = fexp2(strans[q0 * NTAG + p + 16] * LOG2E);
        float E0_10 = fexp2(strans[(q0 + 16) * NTAG + p] * LOG2E);
        float E0_11 = fexp2(strans[(q0 + 16) * NTAG + p + 16] * LOG2E);
        REPEAT15(DECL_E)

        const float tS2lo = strans[p * NTAG + STOP] * LOG2E;
        const float tS2hi = strans[(p + 16) * NTAG + STOP] * LOG2E;

        const int n = wsl[b];             // uniform within the 16-lane group
        const int nm1 = n - 1;
        int nmax = n;
        { int o = __shfl_xor(nmax, 16, 64); nmax = nmax > o ? nmax : o;
          o = __shfl_xor(nmax, 32, 64); nmax = nmax > o ? nmax : o; }
        nmax = __builtin_amdgcn_readfirstlane(nmax);

        const float* __restrict__ frow = feats + (size_t)b * L * NTAG;

        // init (t = 0)
        float S_lo = fexp2((strans[START * NTAG + p] + frow[p]) * LOG2E);
        float S_hi = fexp2((strans[START * NTAG + p + 16] + frow[p + 16]) * LOG2E);
        int M2i = 0;
        float SfL = S_lo, SfH = S_hi;     // snapshot at t == n-1 (covers n==1)
        int M2f = 0;

        // 8 named prefetch slot pairs; invariant at loop head: f k = feat(t+k)
#define LDF2(t_, sl, sh) { const int tc_ = ((t_) < L - 1) ? (t_) : (L - 1); \
                           const float* ap_ = frow + tc_ * NTAG + p; \
                           sl = ap_[0]; sh = ap_[16]; }
        float f0L, f0H, f1L, f1H, f2L, f2H, f3L, f3H,
              f4L, f4H, f5L, f5H, f6L, f6H, f7L, f7H;
        LDF2(1, f0L, f0H) LDF2(2, f1L, f1H) LDF2(3, f2L, f2H) LDF2(4, f3L, f3H)
        LDF2(5, f4L, f4H) LDF2(6, f5L, f5H) LDF2(7, f6L, f6H) LDF2(8, f7L, f7H)
#undef LDF2

        int t = 1;
        for (; t + 8 <= nmax; t += 8) {
            STEP_RELOAD(f0L, f0H, t + 0, t + 8,  0)
            STEP_RELOAD(f1L, f1H, t + 1, t + 9,  0)
            STEP_RELOAD(f2L, f2H, t + 2, t + 10, 0)
            STEP_RELOAD(f3L, f3H, t + 3, t + 11, 1)  // exact pow2 renorm /4
            STEP_RELOAD(f4L, f4H, t + 4, t + 12, 0)
            STEP_RELOAD(f5L, f5H, t + 5, t + 13, 0)
            STEP_RELOAD(f6L, f6H, t + 6, t + 14, 0)
            STEP_RELOAD(f7L, f7H, t + 7, t + 15, 1)
        }
        // epilogue: remaining nmax-t in [0,8)
        if (t + 0 < nmax) { STEP_NORELOAD(f0L, f0H, t + 0, 1) }
        if (t + 1 < nmax) { STEP_NORELOAD(f1L, f1H, t + 1, 1) }
        if (t + 2 < nmax) { STEP_NORELOAD(f2L, f2H, t + 2, 1) }
        if (t + 3 < nmax) { STEP_NORELOAD(f3L, f3H, t + 3, 1) }
        if (t + 4 < nmax) { STEP_NORELOAD(f4L, f4H, t + 4, 1) }
        if (t + 5 < nmax) { STEP_NORELOAD(f5L, f5H, t + 5, 1) }
        if (t + 6 < nmax) { STEP_NORELOAD(f6L, f6H, t + 6, 1) }

        // forward score: ln2 * (M2f + log2 sum_j Sf_j * 2^(trans[j,STOP]*log2e))
        float ex = SfL * fexp2(tS2lo) + SfH * fexp2(tS2hi);
        // 16-lane rotate-add all-reduce (direction-agnostic)
        asm volatile("s_nop 1\n\t"
            "v_add_f32 %0, %0, %0 row_ror:1\n\ts_nop 1\n\t"
            "v_add_f32 %0, %0, %0 row_ror:2\n\ts_nop 1\n\t"
            "v_add_f32 %0, %0, %0 row_ror:4\n\ts_nop 1\n\t"
            "v_add_f32 %0, %0, %0 row_ror:8" : "+v"(ex));
        if (p == 0 && bok) atomicAdd(out, LN2 * ((float)M2f + flog2(ex)));
    } else {
        // ================= gold waves (pure gathers) ========================
        for (int bi = wave - 1; bi < 4; bi += 3) {
            const int b = blockIdx.x * 4 + bi;
            if (b >= B) continue;
            const int n = wsl[b];
            const float* __restrict__ frow = feats + (size_t)b * L * NTAG;
            const int*   __restrict__ trow = tags  + (size_t)b * L;

            float acc = 0.f;
            for (int tt = lane; tt < L; tt += 64) {
                const int tg = trow[tt];
                if (tt == 0) {
                    acc += strans[START * NTAG + tg] + frow[tg];
                } else if (tt < n) {
                    const int tgp = trow[tt - 1];
                    acc += strans[tgp * NTAG + tg] + frow[tt * NTAG + tg];
                }
                if (tt == n - 1) {
                    acc += strans[tg * NTAG + STOP];
                }
            }
#pragma unroll
            for (int k = 1; k < 64; k <<= 1) acc += __shfl_xor(acc, k, 64);
            if (lane == 0) atomicAdd(out, -acc);
        }
    }
}

extern "C" void kernel_launch(void* const* d_in, const int* in_sizes, int n_in,
                              void* d_out, int out_size, void* d_ws, size_t ws_size,
                              hipStream_t stream) {
    const float* feats = (const float*)d_in[0];
    const float* trans = (const float*)d_in[1];
    const int*   tags  = (const int*)d_in[2];
    const int*   wsl   = (const int*)d_in[3];
    float* out = (float*)d_out;

    const int B = in_sizes[3];              // word_seq_lens: (B,)
    const int L = in_sizes[2] / B;          // tags: (B, L)

    (void)hipMemsetAsync(out, 0, sizeof(float), stream);
    const int grid = (B + 3) / 4;
    crf_nll_kernel<<<grid, 256, 0, stream>>>(feats, trans, tags, wsl, out, B, L);
}

// Round 5
// 163.669 us; speedup vs baseline: 1.2593x; 1.1625x over previous
//
#include <hip/hip_runtime.h>

#define NTAG 32
#define START 30
#define STOP 31
#define LOG2E 1.44269504088896340736f
#define LN2 0.69314718055994530942f

__device__ __forceinline__ float fexp2(float x) {
#if __has_builtin(__builtin_amdgcn_exp2f)
    return __builtin_amdgcn_exp2f(x);   // v_exp_f32: 2^x
#else
    return exp2f(x);
#endif
}
__device__ __forceinline__ float flog2(float x) {
#if __has_builtin(__builtin_amdgcn_logf)
    return __builtin_amdgcn_logf(x);    // v_log_f32: log2(x)
#else
    return log2f(x);
#endif
}

#define REPEAT32(M) \
    M(0) M(1) M(2) M(3) M(4) M(5) M(6) M(7) \
    M(8) M(9) M(10) M(11) M(12) M(13) M(14) M(15) \
    M(16) M(17) M(18) M(19) M(20) M(21) M(22) M(23) \
    M(24) M(25) M(26) M(27) M(28) M(29) M(30) M(31)

// batched readlanes of linear state Y (all before any FMA)
#define RL_DECL(i) const int su_##i = __builtin_amdgcn_readlane(yint_, (i));
// 4-way accumulator FMA block
#define FMA_T(i) { const float sf_ = __int_as_float(su_##i); \
    if      (((i) & 3) == 0) a0_ = fmaf(sf_, ET2_##i, a0_); \
    else if (((i) & 3) == 1) a1_ = fmaf(sf_, ET2_##i, a1_); \
    else if (((i) & 3) == 2) a2_ = fmaf(sf_, ET2_##i, a2_); \
    else                     a3_ = fmaf(sf_, ET2_##i, a3_); }

// One LINEAR-domain step.  PRE=0 (forward):  S <- (M^T S) * F
//                          PRE=1 (backward): S <- M (S * F)   [ET2 transposed]
// RN: exact pow2 renorm via lane0 exponent subtract (uniform), counted in M2i.
#define STEP_CORE(fraw_, PRE, RN) { \
    const float F_ = fexp2((fraw_) * LOG2E); \
    const float ybc_ = (PRE) ? (S * F_) : S; \
    const int yint_ = __float_as_int(ybc_); \
    REPEAT32(RL_DECL) \
    float a0_ = 0.f, a1_ = 0.f, a2_ = 0.f, a3_ = 0.f; \
    REPEAT32(FMA_T) \
    const float r_ = ((a0_ + a1_) + (a2_ + a3_)); \
    S = (PRE) ? r_ : (r_ * F_); \
    if (RN) { \
        const int b0_ = __builtin_amdgcn_readfirstlane(__float_as_int(S)); \
        const int k_ = ((b0_ >> 23) & 0xff) - 127; \
        S = __int_as_float(__float_as_int(S) - (k_ << 23)); \
        M2i += k_; } }

// forward: consume FS, reload with time index tload (16 steps ahead, clamped up)
#define STEP_RELOAD_F(FS, tload, RN) { const float fraw_ = FS; \
    { const int tc_ = ((tload) < L - 1) ? (tload) : (L - 1); \
      FS = frow[tc_ * NTAG + j]; } \
    STEP_CORE(fraw_, 0, RN) }
// backward: consume FS, reload with time index tload (16 steps behind, clamped at 0)
#define STEP_RELOAD_B(FS, tload, RN) { const float fraw_ = FS; \
    { const int tc_ = ((tload) > 0) ? (tload) : 0; \
      FS = frow[tc_ * NTAG + j]; } \
    STEP_CORE(fraw_, 1, RN) }

#define STEP_NR_F(FS, RN) { const float fraw_ = FS; STEP_CORE(fraw_, 0, RN) }
#define STEP_NR_B(FS, RN) { const float fraw_ = FS; STEP_CORE(fraw_, 1, RN) }

// zero-instruction insurance against ET2 remat/spill
#define PIN_ET2 \
    asm volatile("" : "+v"(ET2_0),  "+v"(ET2_1),  "+v"(ET2_2),  "+v"(ET2_3), \
                      "+v"(ET2_4),  "+v"(ET2_5),  "+v"(ET2_6),  "+v"(ET2_7)); \
    asm volatile("" : "+v"(ET2_8),  "+v"(ET2_9),  "+v"(ET2_10), "+v"(ET2_11), \
                      "+v"(ET2_12), "+v"(ET2_13), "+v"(ET2_14), "+v"(ET2_15)); \
    asm volatile("" : "+v"(ET2_16), "+v"(ET2_17), "+v"(ET2_18), "+v"(ET2_19), \
                      "+v"(ET2_20), "+v"(ET2_21), "+v"(ET2_22), "+v"(ET2_23)); \
    asm volatile("" : "+v"(ET2_24), "+v"(ET2_25), "+v"(ET2_26), "+v"(ET2_27), \
                      "+v"(ET2_28), "+v"(ET2_29), "+v"(ET2_30), "+v"(ET2_31));

// Block = 768 threads = 12 waves, grid = B/4 = 256 blocks = 1 block/CU.
// Waves 0-3: FORWARD half-chains (batch blk*4+w), steps t=1..h-1, h=(n+1)/2.
// Waves 4-7: BACKWARD half-chains (same batches), steps t=n-1..h.
// Waves 8-11: gold-score gathers.
// Wave i -> SIMD i&3: each SIMD gets one fwd + one bwd + one gold wave ->
// two co-resident half-chains interleave their ~6cy/instr issue cadence.
// fwd/bwd of one batch have equal length -> no barrier skew.
__global__ __launch_bounds__(768, 1) void crf_nll_kernel(
    const float* __restrict__ feats,   // B x L x 32
    const float* __restrict__ trans,   // 32 x 32
    const int*   __restrict__ tags,    // B x L
    const int*   __restrict__ wsl,     // B
    float* __restrict__ out, int B, int L)
{
    __shared__ float strans[NTAG * NTAG];
    __shared__ float sRes[8][NTAG];    // [wave][tag]: fwd S (0-3), bwd x (4-7)
    __shared__ int   sM2[8];
    for (int i = threadIdx.x; i < NTAG * NTAG; i += 768) strans[i] = trans[i];
    __syncthreads();

    const int wave = threadIdx.x >> 6;
    const int lane = threadIdx.x & 63;

    if (wave < 8) {
        const int dir = wave >> 2;            // 0 = fwd, 1 = bwd
        int b = blockIdx.x * 4 + (wave & 3);
        if (b >= B) b = B - 1;
        b = __builtin_amdgcn_readfirstlane(b);
        if (lane < 32) {
            const int j = lane;
            const int n = __builtin_amdgcn_readfirstlane(wsl[b]);
            const int h = (n + 1) >> 1;       // meet point
            const float* __restrict__ frow = feats + (size_t)b * L * NTAG;
            float S;
            int M2i = 0;

            if (dir == 0) {
                // ============== forward: S(0) -> S(h-1), cnt = h-1 steps =====
#define DECL_ET2(i) float ET2_##i = fexp2(strans[(i) * NTAG + j] * LOG2E);
                REPEAT32(DECL_ET2)
#undef DECL_ET2
                S = fexp2((strans[START * NTAG + j] + frow[j]) * LOG2E);
#define LDF(t_) frow[(((t_) < L - 1) ? (t_) : (L - 1)) * NTAG + j]
                float fA0 = LDF(1),  fA1 = LDF(2),  fA2 = LDF(3),  fA3 = LDF(4),
                      fA4 = LDF(5),  fA5 = LDF(6),  fA6 = LDF(7),  fA7 = LDF(8);
                float fB0 = LDF(9),  fB1 = LDF(10), fB2 = LDF(11), fB3 = LDF(12),
                      fB4 = LDF(13), fB5 = LDF(14), fB6 = LDF(15), fB7 = LDF(16);
#undef LDF
                int t = 1;
                for (; t + 16 <= h; t += 16) {
                    PIN_ET2
                    STEP_RELOAD_F(fA0, t + 16, 0)
                    STEP_RELOAD_F(fA1, t + 17, 0)
                    STEP_RELOAD_F(fA2, t + 18, 0)
                    STEP_RELOAD_F(fA3, t + 19, 1)
                    STEP_RELOAD_F(fA4, t + 20, 0)
                    STEP_RELOAD_F(fA5, t + 21, 0)
                    STEP_RELOAD_F(fA6, t + 22, 0)
                    STEP_RELOAD_F(fA7, t + 23, 1)
                    STEP_RELOAD_F(fB0, t + 24, 0)
                    STEP_RELOAD_F(fB1, t + 25, 0)
                    STEP_RELOAD_F(fB2, t + 26, 0)
                    STEP_RELOAD_F(fB3, t + 27, 1)
                    STEP_RELOAD_F(fB4, t + 28, 0)
                    STEP_RELOAD_F(fB5, t + 29, 0)
                    STEP_RELOAD_F(fB6, t + 30, 0)
                    STEP_RELOAD_F(fB7, t + 31, 1)
                }
                if (t + 0  < h) { STEP_NR_F(fA0, 1) }
                if (t + 1  < h) { STEP_NR_F(fA1, 1) }
                if (t + 2  < h) { STEP_NR_F(fA2, 1) }
                if (t + 3  < h) { STEP_NR_F(fA3, 1) }
                if (t + 4  < h) { STEP_NR_F(fA4, 1) }
                if (t + 5  < h) { STEP_NR_F(fA5, 1) }
                if (t + 6  < h) { STEP_NR_F(fA6, 1) }
                if (t + 7  < h) { STEP_NR_F(fA7, 1) }
                if (t + 8  < h) { STEP_NR_F(fB0, 1) }
                if (t + 9  < h) { STEP_NR_F(fB1, 1) }
                if (t + 10 < h) { STEP_NR_F(fB2, 1) }
                if (t + 11 < h) { STEP_NR_F(fB3, 1) }
                if (t + 12 < h) { STEP_NR_F(fB4, 1) }
                if (t + 13 < h) { STEP_NR_F(fB5, 1) }
                if (t + 14 < h) { STEP_NR_F(fB6, 1) }
            } else {
                // ============== backward: x = u, t = n-1 .. h, cnt = n-h =====
                // x_new[j] = sum_i (x_i * F_{t,i}) * exp(trans[j][i])
#define DECL_ET2(i) float ET2_##i = fexp2(strans[j * NTAG + (i)] * LOG2E);
                REPEAT32(DECL_ET2)
#undef DECL_ET2
                S = fexp2(strans[j * NTAG + STOP] * LOG2E);   // u_j
                const int cnt = n - h;
#define LDB(s_) frow[(((n - 1 - (s_)) > 0) ? (n - 1 - (s_)) : 0) * NTAG + j]
                float gA0 = LDB(0),  gA1 = LDB(1),  gA2 = LDB(2),  gA3 = LDB(3),
                      gA4 = LDB(4),  gA5 = LDB(5),  gA6 = LDB(6),  gA7 = LDB(7);
                float gB0 = LDB(8),  gB1 = LDB(9),  gB2 = LDB(10), gB3 = LDB(11),
                      gB4 = LDB(12), gB5 = LDB(13), gB6 = LDB(14), gB7 = LDB(15);
#undef LDB
                int s = 0;
                for (; s + 16 <= cnt; s += 16) {
                    PIN_ET2
                    STEP_RELOAD_B(gA0, n - 1 - (s + 0)  - 16, 0)
                    STEP_RELOAD_B(gA1, n - 1 - (s + 1)  - 16, 0)
                    STEP_RELOAD_B(gA2, n - 1 - (s + 2)  - 16, 0)
                    STEP_RELOAD_B(gA3, n - 1 - (s + 3)  - 16, 1)
                    STEP_RELOAD_B(gA4, n - 1 - (s + 4)  - 16, 0)
                    STEP_RELOAD_B(gA5, n - 1 - (s + 5)  - 16, 0)
                    STEP_RELOAD_B(gA6, n - 1 - (s + 6)  - 16, 0)
                    STEP_RELOAD_B(gA7, n - 1 - (s + 7)  - 16, 1)
                    STEP_RELOAD_B(gB0, n - 1 - (s + 8)  - 16, 0)
                    STEP_RELOAD_B(gB1, n - 1 - (s + 9)  - 16, 0)
                    STEP_RELOAD_B(gB2, n - 1 - (s + 10) - 16, 0)
                    STEP_RELOAD_B(gB3, n - 1 - (s + 11) - 16, 1)
                    STEP_RELOAD_B(gB4, n - 1 - (s + 12) - 16, 0)
                    STEP_RELOAD_B(gB5, n - 1 - (s + 13) - 16, 0)
                    STEP_RELOAD_B(gB6, n - 1 - (s + 14) - 16, 0)
                    STEP_RELOAD_B(gB7, n - 1 - (s + 15) - 16, 1)
                }
                if (s + 0  < cnt) { STEP_NR_B(gA0, 1) }
                if (s + 1  < cnt) { STEP_NR_B(gA1, 1) }
                if (s + 2  < cnt) { STEP_NR_B(gA2, 1) }
                if (s + 3  < cnt) { STEP_NR_B(gA3, 1) }
                if (s + 4  < cnt) { STEP_NR_B(gA4, 1) }
                if (s + 5  < cnt) { STEP_NR_B(gA5, 1) }
                if (s + 6  < cnt) { STEP_NR_B(gA6, 1) }
                if (s + 7  < cnt) { STEP_NR_B(gA7, 1) }
                if (s + 8  < cnt) { STEP_NR_B(gB0, 1) }
                if (s + 9  < cnt) { STEP_NR_B(gB1, 1) }
                if (s + 10 < cnt) { STEP_NR_B(gB2, 1) }
                if (s + 11 < cnt) { STEP_NR_B(gB3, 1) }
                if (s + 12 < cnt) { STEP_NR_B(gB4, 1) }
                if (s + 13 < cnt) { STEP_NR_B(gB5, 1) }
                if (s + 14 < cnt) { STEP_NR_B(gB6, 1) }
            }
            sRes[wave][j] = S;
            if (j == 0) sM2[wave] = M2i;
        }
    } else {
        // ================= gold waves (pure gathers) ========================
        int b = blockIdx.x * 4 + (wave - 8);
        if (b < B) {
            b = __builtin_amdgcn_readfirstlane(b);
            const int n = wsl[b];
            const float* __restrict__ frow = feats + (size_t)b * L * NTAG;
            const int*   __restrict__ trow = tags  + (size_t)b * L;
            float acc = 0.f;
            for (int tt = lane; tt < L; tt += 64) {
                const int tg = trow[tt];
                if (tt == 0) {
                    acc += strans[START * NTAG + tg] + frow[tg];
                } else if (tt < n) {
                    const int tgp = trow[tt - 1];
                    acc += strans[tgp * NTAG + tg] + frow[tt * NTAG + tg];
                }
                if (tt == n - 1) {
                    acc += strans[tg * NTAG + STOP];
                }
            }
#pragma unroll
            for (int k = 1; k < 64; k <<= 1) acc += __shfl_xor(acc, k, 64);
            if (lane == 0) atomicAdd(out, -acc);
        }
    }

    __syncthreads();

    // ============== combine: forward score = ln2*(M2f+M2b+log2(x . S)) ======
    if (wave < 4) {
        const int b = blockIdx.x * 4 + wave;
        if (b < B && lane < 32) {
            float ex = sRes[wave][lane] * sRes[wave + 4][lane];
#pragma unroll
            for (int k = 1; k < 32; k <<= 1) ex += __shfl_xor(ex, k, 32);
            if (lane == 0)
                atomicAdd(out, LN2 * ((float)(sM2[wave] + sM2[wave + 4]) + flog2(ex)));
        }
    }
}

extern "C" void kernel_launch(void* const* d_in, const int* in_sizes, int n_in,
                              void* d_out, int out_size, void* d_ws, size_t ws_size,
                              hipStream_t stream) {
    const float* feats = (const float*)d_in[0];
    const float* trans = (const float*)d_in[1];
    const int*   tags  = (const int*)d_in[2];
    const int*   wsl   = (const int*)d_in[3];
    float* out = (float*)d_out;

    const int B = in_sizes[3];              // word_seq_lens: (B,)
    const int L = in_sizes[2] / B;          // tags: (B, L)

    (void)hipMemsetAsync(out, 0, sizeof(float), stream);
    const int grid = (B + 3) / 4;
    crf_nll_kernel<<<grid, 768, 0, stream>>>(feats, trans, tags, wsl, out, B, L);
}

// Round 6
// 139.179 us; speedup vs baseline: 1.4808x; 1.1760x over previous
//
#include <hip/hip_runtime.h>

#define NTAG 32
#define START 30
#define STOP 31
#define LOG2E 1.44269504088896340736f
#define LN2 0.69314718055994530942f

typedef float f2 __attribute__((ext_vector_type(2)));
typedef float f4 __attribute__((ext_vector_type(4)));

__device__ __forceinline__ float fexp2(float x) {
#if __has_builtin(__builtin_amdgcn_exp2f)
    return __builtin_amdgcn_exp2f(x);   // v_exp_f32: 2^x
#else
    return exp2f(x);
#endif
}
__device__ __forceinline__ float flog2(float x) {
#if __has_builtin(__builtin_amdgcn_logf)
    return __builtin_amdgcn_logf(x);    // v_log_f32: log2(x)
#else
    return log2f(x);
#endif
}

// packed 2xf32 math (VOP3P): halves FMA instruction count on the chain
#define PKMUL(d, s, e) asm("v_pk_mul_f32 %0, %1, %2" : "=v"(d) : "v"(s), "v"(e))
#define PKFMA(d, s, e) asm("v_pk_fma_f32 %0, %1, %2, %0" : "+v"(d) : "v"(s), "v"(e))
#define PKADD(d, x, y) asm("v_pk_add_f32 %0, %1, %2" : "=v"(d) : "v"(x), "v"(y))

#define REPEAT16(M) \
    M(0) M(1) M(2) M(3) M(4) M(5) M(6) M(7) \
    M(8) M(9) M(10) M(11) M(12) M(13) M(14) M(15)

// One LINEAR-domain step.  PRE=0 (forward):  S <- (M^T S) * F
//                          PRE=1 (backward): S <- M (S * F)   [E2 transposed]
// Broadcast: own value -> LDS (ds_write_b32), full vector back via 8x
// uniform-address ds_read_b128 (pure broadcast, conflict-free).  Same-wave
// DS ops are ordered; the memory-clobber asm pins store-before-loads at the
// compiler level.  Matvec: 16 pk ops (pairs i=2m,2m+1), 4-way acc ILP.
// RN: exact pow2 renorm keyed off broadcast Q0.x (= lane0 value, uniform).
#define STEP_CORE(fraw_, PRE, RN) { \
    const float F_ = fexp2((fraw_) * LOG2E); \
    const float y_ = (PRE) ? (S * F_) : S; \
    *swr = y_; \
    asm volatile("" ::: "memory"); \
    const f4 Q0 = srd4[0], Q1 = srd4[1], Q2 = srd4[2], Q3 = srd4[3], \
             Q4 = srd4[4], Q5 = srd4[5], Q6 = srd4[6], Q7 = srd4[7]; \
    const f2 s0  = __builtin_shufflevector(Q0, Q0, 0, 1), s1  = __builtin_shufflevector(Q0, Q0, 2, 3); \
    const f2 s2  = __builtin_shufflevector(Q1, Q1, 0, 1), s3  = __builtin_shufflevector(Q1, Q1, 2, 3); \
    const f2 s4  = __builtin_shufflevector(Q2, Q2, 0, 1), s5  = __builtin_shufflevector(Q2, Q2, 2, 3); \
    const f2 s6  = __builtin_shufflevector(Q3, Q3, 0, 1), s7  = __builtin_shufflevector(Q3, Q3, 2, 3); \
    const f2 s8  = __builtin_shufflevector(Q4, Q4, 0, 1), s9  = __builtin_shufflevector(Q4, Q4, 2, 3); \
    const f2 s10 = __builtin_shufflevector(Q5, Q5, 0, 1), s11 = __builtin_shufflevector(Q5, Q5, 2, 3); \
    const f2 s12 = __builtin_shufflevector(Q6, Q6, 0, 1), s13 = __builtin_shufflevector(Q6, Q6, 2, 3); \
    const f2 s14 = __builtin_shufflevector(Q7, Q7, 0, 1), s15 = __builtin_shufflevector(Q7, Q7, 2, 3); \
    f2 a0, a1, a2, a3; \
    PKMUL(a0, s0,  E2_0);  PKMUL(a1, s1,  E2_1);  PKMUL(a2, s2,  E2_2);  PKMUL(a3, s3,  E2_3); \
    PKFMA(a0, s4,  E2_4);  PKFMA(a1, s5,  E2_5);  PKFMA(a2, s6,  E2_6);  PKFMA(a3, s7,  E2_7); \
    PKFMA(a0, s8,  E2_8);  PKFMA(a1, s9,  E2_9);  PKFMA(a2, s10, E2_10); PKFMA(a3, s11, E2_11); \
    PKFMA(a0, s12, E2_12); PKFMA(a1, s13, E2_13); PKFMA(a2, s14, E2_14); PKFMA(a3, s15, E2_15); \
    f2 t01, t23, tt; \
    PKADD(t01, a0, a1); PKADD(t23, a2, a3); PKADD(tt, t01, t23); \
    const float r_ = tt.x + tt.y; \
    S = (PRE) ? r_ : (r_ * F_); \
    if (RN) { \
        const int k_ = ((__float_as_int(Q0.x) >> 23) & 0xff) - 127; \
        S = __int_as_float(__float_as_int(S) - (k_ << 23)); \
        M2i += k_; } }

// forward: consume FS, reload with time index tload (16 steps ahead, clamped up)
#define STEP_RELOAD_F(FS, tload, RN) { const float fraw_ = FS; \
    { const int tc_ = ((tload) < L - 1) ? (tload) : (L - 1); \
      FS = frow[tc_ * NTAG + j]; } \
    STEP_CORE(fraw_, 0, RN) }
// backward: consume FS, reload with time index tload (16 steps behind, clamped at 0)
#define STEP_RELOAD_B(FS, tload, RN) { const float fraw_ = FS; \
    { const int tc_ = ((tload) > 0) ? (tload) : 0; \
      FS = frow[tc_ * NTAG + j]; } \
    STEP_CORE(fraw_, 1, RN) }

#define STEP_NR_F(FS, RN) { const float fraw_ = FS; STEP_CORE(fraw_, 0, RN) }
#define STEP_NR_B(FS, RN) { const float fraw_ = FS; STEP_CORE(fraw_, 1, RN) }

// zero-instruction insurance against E2 remat/spill
#define PIN_E2 \
    asm volatile("" : "+v"(E2_0),  "+v"(E2_1),  "+v"(E2_2),  "+v"(E2_3), \
                      "+v"(E2_4),  "+v"(E2_5),  "+v"(E2_6),  "+v"(E2_7)); \
    asm volatile("" : "+v"(E2_8),  "+v"(E2_9),  "+v"(E2_10), "+v"(E2_11), \
                      "+v"(E2_12), "+v"(E2_13), "+v"(E2_14), "+v"(E2_15));

// Block = 768 threads = 12 waves, grid = B/4 = 256 blocks = 1 block/CU.
// Waves 0-3: FORWARD half-chains (batch blk*4+w), steps t=1..h-1, h=(n+1)/2.
// Waves 4-7: BACKWARD half-chains (same batches), steps t=n-1..h.
// Waves 8-11: gold-score gathers.
// Wave i -> SIMD i&3: each SIMD gets one fwd + one bwd chain wave; each
// wave's DS round-trip is a true s_waitcnt sleep that frees the issue port
// for the sibling wave's pk-FMA burst (unlike readlane hazard bubbles).
__global__ __launch_bounds__(768, 1) void crf_nll_kernel(
    const float* __restrict__ feats,   // B x L x 32
    const float* __restrict__ trans,   // 32 x 32
    const int*   __restrict__ tags,    // B x L
    const int*   __restrict__ wsl,     // B
    float* __restrict__ out, int B, int L)
{
    __shared__ float strans[NTAG * NTAG];
    __shared__ __align__(16) float sBC[8][NTAG];   // per-wave broadcast buffer
    __shared__ float sRes[8][NTAG];    // [wave][tag]: fwd S (0-3), bwd x (4-7)
    __shared__ int   sM2[8];
    for (int i = threadIdx.x; i < NTAG * NTAG; i += 768) strans[i] = trans[i];
    __syncthreads();

    const int wave = threadIdx.x >> 6;
    const int lane = threadIdx.x & 63;

    if (wave < 8) {
        const int dir = wave >> 2;            // 0 = fwd, 1 = bwd
        int b = blockIdx.x * 4 + (wave & 3);
        if (b >= B) b = B - 1;
        b = __builtin_amdgcn_readfirstlane(b);
        if (lane < 32) {
            const int j = lane;
            const int n = __builtin_amdgcn_readfirstlane(wsl[b]);
            const int h = (n + 1) >> 1;       // meet point
            const float* __restrict__ frow = feats + (size_t)b * L * NTAG;
            float* const swr = &sBC[wave][j];
            const f4* const srd4 = (const f4*)&sBC[wave][0];
            float S;
            int M2i = 0;

            if (dir == 0) {
                // ============== forward: S(0) -> S(h-1), cnt = h-1 steps =====
                // E2_k = { exp2(trans[2k][j]*log2e), exp2(trans[2k+1][j]*log2e) }
#define DECL_E2(k) f2 E2_##k = { fexp2(strans[(2*(k)) * NTAG + j] * LOG2E), \
                                 fexp2(strans[(2*(k)+1) * NTAG + j] * LOG2E) };
                REPEAT16(DECL_E2)
#undef DECL_E2
                S = fexp2((strans[START * NTAG + j] + frow[j]) * LOG2E);
#define LDF(t_) frow[(((t_) < L - 1) ? (t_) : (L - 1)) * NTAG + j]
                float fA0 = LDF(1),  fA1 = LDF(2),  fA2 = LDF(3),  fA3 = LDF(4),
                      fA4 = LDF(5),  fA5 = LDF(6),  fA6 = LDF(7),  fA7 = LDF(8);
                float fB0 = LDF(9),  fB1 = LDF(10), fB2 = LDF(11), fB3 = LDF(12),
                      fB4 = LDF(13), fB5 = LDF(14), fB6 = LDF(15), fB7 = LDF(16);
#undef LDF
                int t = 1;
                for (; t + 16 <= h; t += 16) {
                    PIN_E2
                    STEP_RELOAD_F(fA0, t + 16, 0)
                    STEP_RELOAD_F(fA1, t + 17, 0)
                    STEP_RELOAD_F(fA2, t + 18, 0)
                    STEP_RELOAD_F(fA3, t + 19, 1)   // exact pow2 renorm /4
                    STEP_RELOAD_F(fA4, t + 20, 0)
                    STEP_RELOAD_F(fA5, t + 21, 0)
                    STEP_RELOAD_F(fA6, t + 22, 0)
                    STEP_RELOAD_F(fA7, t + 23, 1)
                    STEP_RELOAD_F(fB0, t + 24, 0)
                    STEP_RELOAD_F(fB1, t + 25, 0)
                    STEP_RELOAD_F(fB2, t + 26, 0)
                    STEP_RELOAD_F(fB3, t + 27, 1)
                    STEP_RELOAD_F(fB4, t + 28, 0)
                    STEP_RELOAD_F(fB5, t + 29, 0)
                    STEP_RELOAD_F(fB6, t + 30, 0)
                    STEP_RELOAD_F(fB7, t + 31, 1)
                }
                if (t + 0  < h) { STEP_NR_F(fA0, 1) }
                if (t + 1  < h) { STEP_NR_F(fA1, 1) }
                if (t + 2  < h) { STEP_NR_F(fA2, 1) }
                if (t + 3  < h) { STEP_NR_F(fA3, 1) }
                if (t + 4  < h) { STEP_NR_F(fA4, 1) }
                if (t + 5  < h) { STEP_NR_F(fA5, 1) }
                if (t + 6  < h) { STEP_NR_F(fA6, 1) }
                if (t + 7  < h) { STEP_NR_F(fA7, 1) }
                if (t + 8  < h) { STEP_NR_F(fB0, 1) }
                if (t + 9  < h) { STEP_NR_F(fB1, 1) }
                if (t + 10 < h) { STEP_NR_F(fB2, 1) }
                if (t + 11 < h) { STEP_NR_F(fB3, 1) }
                if (t + 12 < h) { STEP_NR_F(fB4, 1) }
                if (t + 13 < h) { STEP_NR_F(fB5, 1) }
                if (t + 14 < h) { STEP_NR_F(fB6, 1) }
            } else {
                // ============== backward: x = u, t = n-1 .. h, cnt = n-h =====
                // x_new[j] = sum_i (x_i * F_{t,i}) * exp(trans[j][i]) -> transposed E2
#define DECL_E2(k) f2 E2_##k = { fexp2(strans[j * NTAG + (2*(k))] * LOG2E), \
                                 fexp2(strans[j * NTAG + (2*(k)+1)] * LOG2E) };
                REPEAT16(DECL_E2)
#undef DECL_E2
                S = fexp2(strans[j * NTAG + STOP] * LOG2E);   // u_j
                const int cnt = n - h;
#define LDB(s_) frow[(((n - 1 - (s_)) > 0) ? (n - 1 - (s_)) : 0) * NTAG + j]
                float gA0 = LDB(0),  gA1 = LDB(1),  gA2 = LDB(2),  gA3 = LDB(3),
                      gA4 = LDB(4),  gA5 = LDB(5),  gA6 = LDB(6),  gA7 = LDB(7);
                float gB0 = LDB(8),  gB1 = LDB(9),  gB2 = LDB(10), gB3 = LDB(11),
                      gB4 = LDB(12), gB5 = LDB(13), gB6 = LDB(14), gB7 = LDB(15);
#undef LDB
                int s = 0;
                for (; s + 16 <= cnt; s += 16) {
                    PIN_E2
                    STEP_RELOAD_B(gA0, n - 1 - (s + 0)  - 16, 0)
                    STEP_RELOAD_B(gA1, n - 1 - (s + 1)  - 16, 0)
                    STEP_RELOAD_B(gA2, n - 1 - (s + 2)  - 16, 0)
                    STEP_RELOAD_B(gA3, n - 1 - (s + 3)  - 16, 1)
                    STEP_RELOAD_B(gA4, n - 1 - (s + 4)  - 16, 0)
                    STEP_RELOAD_B(gA5, n - 1 - (s + 5)  - 16, 0)
                    STEP_RELOAD_B(gA6, n - 1 - (s + 6)  - 16, 0)
                    STEP_RELOAD_B(gA7, n - 1 - (s + 7)  - 16, 1)
                    STEP_RELOAD_B(gB0, n - 1 - (s + 8)  - 16, 0)
                    STEP_RELOAD_B(gB1, n - 1 - (s + 9)  - 16, 0)
                    STEP_RELOAD_B(gB2, n - 1 - (s + 10) - 16, 0)
                    STEP_RELOAD_B(gB3, n - 1 - (s + 11) - 16, 1)
                    STEP_RELOAD_B(gB4, n - 1 - (s + 12) - 16, 0)
                    STEP_RELOAD_B(gB5, n - 1 - (s + 13) - 16, 0)
                    STEP_RELOAD_B(gB6, n - 1 - (s + 14) - 16, 0)
                    STEP_RELOAD_B(gB7, n - 1 - (s + 15) - 16, 1)
                }
                if (s + 0  < cnt) { STEP_NR_B(gA0, 1) }
                if (s + 1  < cnt) { STEP_NR_B(gA1, 1) }
                if (s + 2  < cnt) { STEP_NR_B(gA2, 1) }
                if (s + 3  < cnt) { STEP_NR_B(gA3, 1) }
                if (s + 4  < cnt) { STEP_NR_B(gA4, 1) }
                if (s + 5  < cnt) { STEP_NR_B(gA5, 1) }
                if (s + 6  < cnt) { STEP_NR_B(gA6, 1) }
                if (s + 7  < cnt) { STEP_NR_B(gA7, 1) }
                if (s + 8  < cnt) { STEP_NR_B(gB0, 1) }
                if (s + 9  < cnt) { STEP_NR_B(gB1, 1) }
                if (s + 10 < cnt) { STEP_NR_B(gB2, 1) }
                if (s + 11 < cnt) { STEP_NR_B(gB3, 1) }
                if (s + 12 < cnt) { STEP_NR_B(gB4, 1) }
                if (s + 13 < cnt) { STEP_NR_B(gB5, 1) }
                if (s + 14 < cnt) { STEP_NR_B(gB6, 1) }
            }
            sRes[wave][j] = S;
            if (j == 0) sM2[wave] = M2i;
        }
    } else {
        // ================= gold waves (pure gathers) ========================
        int b = blockIdx.x * 4 + (wave - 8);
        if (b < B) {
            b = __builtin_amdgcn_readfirstlane(b);
            const int n = wsl[b];
            const float* __restrict__ frow = feats + (size_t)b * L * NTAG;
            const int*   __restrict__ trow = tags  + (size_t)b * L;
            float acc = 0.f;
            for (int tt = lane; tt < L; tt += 64) {
                const int tg = trow[tt];
                if (tt == 0) {
                    acc += strans[START * NTAG + tg] + frow[tg];
                } else if (tt < n) {
                    const int tgp = trow[tt - 1];
                    acc += strans[tgp * NTAG + tg] + frow[tt * NTAG + tg];
                }
                if (tt == n - 1) {
                    acc += strans[tg * NTAG + STOP];
                }
            }
#pragma unroll
            for (int k = 1; k < 64; k <<= 1) acc += __shfl_xor(acc, k, 64);
            if (lane == 0) atomicAdd(out, -acc);
        }
    }

    __syncthreads();

    // ============== combine: forward score = ln2*(M2f+M2b+log2(x . S)) ======
    if (wave < 4) {
        const int b = blockIdx.x * 4 + wave;
        if (b < B && lane < 32) {
            float ex = sRes[wave][lane] * sRes[wave + 4][lane];
#pragma unroll
            for (int k = 1; k < 32; k <<= 1) ex += __shfl_xor(ex, k, 32);
            if (lane == 0)
                atomicAdd(out, LN2 * ((float)(sM2[wave] + sM2[wave + 4]) + flog2(ex)));
        }
    }
}

extern "C" void kernel_launch(void* const* d_in, const int* in_sizes, int n_in,
                              void* d_out, int out_size, void* d_ws, size_t ws_size,
                              hipStream_t stream) {
    const float* feats = (const float*)d_in[0];
    const float* trans = (const float*)d_in[1];
    const int*   tags  = (const int*)d_in[2];
    const int*   wsl   = (const int*)d_in[3];
    float* out = (float*)d_out;

    const int B = in_sizes[3];              // word_seq_lens: (B,)
    const int L = in_sizes[2] / B;          // tags: (B, L)

    (void)hipMemsetAsync(out, 0, sizeof(float), stream);
    const int grid = (B + 3) / 4;
    crf_nll_kernel<<<grid, 768, 0, stream>>>(feats, trans, tags, wsl, out, B, L);
}

// Round 7
// 129.844 us; speedup vs baseline: 1.5873x; 1.0719x over previous
//
#include <hip/hip_runtime.h>

#define NTAG 32
#define START 30
#define STOP 31
#define LOG2E 1.44269504088896340736f
#define LN2 0.69314718055994530942f

typedef float f2 __attribute__((ext_vector_type(2)));
typedef float f4 __attribute__((ext_vector_type(4)));

__device__ __forceinline__ float fexp2(float x) {
#if __has_builtin(__builtin_amdgcn_exp2f)
    return __builtin_amdgcn_exp2f(x);   // v_exp_f32: 2^x
#else
    return exp2f(x);
#endif
}
__device__ __forceinline__ float flog2(float x) {
#if __has_builtin(__builtin_amdgcn_logf)
    return __builtin_amdgcn_logf(x);    // v_log_f32: log2(x)
#else
    return log2f(x);
#endif
}

// Half-exchange between a and b (v_permlane32_swap_b32: low 32 lanes of a
// exchange with high 32 lanes of b).  VALU pipe - no DS latency.  With
// a == b == p on entry, afterwards {a, b} hold {own, other} in SOME order in
// every lane, so a + b == own + other regardless of exchange direction.
__device__ __forceinline__ void plswap(float &a, float &b) {
#if __has_builtin(__builtin_amdgcn_permlane32_swap)
    auto r = __builtin_amdgcn_permlane32_swap(__float_as_int(a), __float_as_int(b),
                                              false, false);
    a = __int_as_float(r[0]);
    b = __int_as_float(r[1]);
#else
    asm volatile("v_permlane32_swap_b32 %0, %1" : "+v"(a), "+v"(b));
#endif
}

// packed 2xf32 math (VOP3P)
#define PKMUL(d, s, e) asm("v_pk_mul_f32 %0, %1, %2" : "=v"(d) : "v"(s), "v"(e))
#define PKFMA(d, s, e) asm("v_pk_fma_f32 %0, %1, %2, %0" : "+v"(d) : "v"(s), "v"(e))
#define PKADD(d, x, y) asm("v_pk_add_f32 %0, %1, %2" : "=v"(d) : "v"(x), "v"(y))

#define REPEAT8(M) M(0) M(1) M(2) M(3) M(4) M(5) M(6) M(7)

// One LINEAR-domain step, dot product SPLIT across wave halves:
// lanes j and j+32 both own output j; lane j handles input terms 0..15,
// lane j+32 terms 16..31 (ib = 0 / 16).  Broadcast: lower lanes write the
// 32 state values to LDS; each half reads back only ITS 16 inputs
// (4x ds_read_b128, two bank-disjoint addresses per instr).  Cross-half
// combine via permlane32_swap (VALU).  PRE=0 fwd: S <- (M^T S)*F;
// PRE=1 bwd: S <- M(S*F).  RN: per-lane exact pow2 renorm (replicas are
// bitwise identical, so k matches across the pair; per-j M2 folded at
// combine with a max-shift).
#define STEP_CORE(fraw_, PRE, RN) { \
    const float F_ = fexp2((fraw_) * LOG2E); \
    const float y_ = (PRE) ? (S * F_) : S; \
    *swr = y_; \
    asm volatile("" ::: "memory"); \
    const f4 Q0 = srd4[0], Q1 = srd4[1], Q2 = srd4[2], Q3 = srd4[3]; \
    const f2 s0 = __builtin_shufflevector(Q0, Q0, 0, 1), s1 = __builtin_shufflevector(Q0, Q0, 2, 3); \
    const f2 s2 = __builtin_shufflevector(Q1, Q1, 0, 1), s3 = __builtin_shufflevector(Q1, Q1, 2, 3); \
    const f2 s4 = __builtin_shufflevector(Q2, Q2, 0, 1), s5 = __builtin_shufflevector(Q2, Q2, 2, 3); \
    const f2 s6 = __builtin_shufflevector(Q3, Q3, 0, 1), s7 = __builtin_shufflevector(Q3, Q3, 2, 3); \
    f2 a0, a1, a2, a3; \
    PKMUL(a0, s0, E2_0); PKMUL(a1, s1, E2_1); PKMUL(a2, s2, E2_2); PKMUL(a3, s3, E2_3); \
    PKFMA(a0, s4, E2_4); PKFMA(a1, s5, E2_5); PKFMA(a2, s6, E2_6); PKFMA(a3, s7, E2_7); \
    f2 t01, t23, tt; \
    PKADD(t01, a0, a1); PKADD(t23, a2, a3); PKADD(tt, t01, t23); \
    const float part_ = tt.x + tt.y; \
    float px_ = part_, py_ = part_; \
    plswap(px_, py_); \
    const float r_ = px_ + py_; \
    S = (PRE) ? r_ : (r_ * F_); \
    if (RN) { \
        const int k_ = ((__float_as_int(S) >> 23) & 0xff) - 127; \
        S = __int_as_float(__float_as_int(S) - (k_ << 23)); \
        M2i += k_; } }

// forward: consume FS, reload with time index tload (16 steps ahead, clamped up)
#define STEP_RELOAD_F(FS, tload, RN) { const float fraw_ = FS; \
    { const int tc_ = ((tload) < L - 1) ? (tload) : (L - 1); \
      FS = frow[tc_ * NTAG + j]; } \
    STEP_CORE(fraw_, 0, RN) }
// backward: consume FS, reload with time index tload (16 steps behind, clamped at 0)
#define STEP_RELOAD_B(FS, tload, RN) { const float fraw_ = FS; \
    { const int tc_ = ((tload) > 0) ? (tload) : 0; \
      FS = frow[tc_ * NTAG + j]; } \
    STEP_CORE(fraw_, 1, RN) }

#define STEP_NR_F(FS, RN) { const float fraw_ = FS; STEP_CORE(fraw_, 0, RN) }
#define STEP_NR_B(FS, RN) { const float fraw_ = FS; STEP_CORE(fraw_, 1, RN) }

// zero-instruction insurance against E2 remat/spill
#define PIN_E2 \
    asm volatile("" : "+v"(E2_0), "+v"(E2_1), "+v"(E2_2), "+v"(E2_3), \
                      "+v"(E2_4), "+v"(E2_5), "+v"(E2_6), "+v"(E2_7));

// Block = 768 threads = 12 waves, grid = B/4 = 256 blocks = 1 block/CU.
// Waves 0-3: FORWARD half-chains (batch blk*4+w), all 64 lanes active
//            (split-dot).  Waves 4-7: BACKWARD half-chains.  Waves 8-11: gold.
// Wave i -> SIMD i&3: each SIMD carries one fwd + one bwd chain wave whose
// DS waits mutually hide (R6-proven), now at ~52 instr/step-pair vs 74.
__global__ __launch_bounds__(768, 1) void crf_nll_kernel(
    const float* __restrict__ feats,   // B x L x 32
    const float* __restrict__ trans,   // 32 x 32
    const int*   __restrict__ tags,    // B x L
    const int*   __restrict__ wsl,     // B
    float* __restrict__ out, int B, int L)
{
    __shared__ float strans[NTAG * NTAG];
    __shared__ __align__(16) float sBC[8][104]; // [wave]: state [0..31], dummy [68..99]
    __shared__ float sRes[8][NTAG];    // fwd S (0-3), bwd x (4-7)
    __shared__ int   sM2[8][NTAG];     // per-j renorm exponents
    for (int i = threadIdx.x; i < NTAG * NTAG; i += 768) strans[i] = trans[i];
    __syncthreads();

    const int wave = threadIdx.x >> 6;
    const int lane = threadIdx.x & 63;

    if (wave < 8) {
        const int dir = wave >> 2;            // 0 = fwd, 1 = bwd
        int b = blockIdx.x * 4 + (wave & 3);
        if (b >= B) b = B - 1;
        b = __builtin_amdgcn_readfirstlane(b);
        const int j = lane & 31;
        const bool up = lane >= 32;
        const int ib = up ? 16 : 0;           // this half's input-term base
        const int n = __builtin_amdgcn_readfirstlane(wsl[b]);
        const int h = (n + 1) >> 1;           // meet point
        const float* __restrict__ frow = feats + (size_t)b * L * NTAG;

        float* const swr = &sBC[wave][(up ? 68 : 0) + j];       // write slot (dummy for upper)
        const f4* const srd4 = (const f4*)&sBC[wave][up ? 16 : 0]; // this half's 16 inputs
        float S;
        int M2i = 0;

        if (dir == 0) {
            // ========== forward: S(0) -> S(h-1), cnt = h-1 steps ============
            // E2_k = e^trans[ib+2k..ib+2k+1][j] (columns of M for output j)
#define DECL_E2(k) f2 E2_##k = { fexp2(strans[(ib + 2*(k)) * NTAG + j] * LOG2E), \
                                 fexp2(strans[(ib + 2*(k) + 1) * NTAG + j] * LOG2E) };
            REPEAT8(DECL_E2)
#undef DECL_E2
            S = fexp2((strans[START * NTAG + j] + frow[j]) * LOG2E);
#define LDF(t_) frow[(((t_) < L - 1) ? (t_) : (L - 1)) * NTAG + j]
            float fA0 = LDF(1),  fA1 = LDF(2),  fA2 = LDF(3),  fA3 = LDF(4),
                  fA4 = LDF(5),  fA5 = LDF(6),  fA6 = LDF(7),  fA7 = LDF(8);
            float fB0 = LDF(9),  fB1 = LDF(10), fB2 = LDF(11), fB3 = LDF(12),
                  fB4 = LDF(13), fB5 = LDF(14), fB6 = LDF(15), fB7 = LDF(16);
#undef LDF
            int t = 1;
            for (; t + 16 <= h; t += 16) {
                PIN_E2
                STEP_RELOAD_F(fA0, t + 16, 0)
                STEP_RELOAD_F(fA1, t + 17, 0)
                STEP_RELOAD_F(fA2, t + 18, 0)
                STEP_RELOAD_F(fA3, t + 19, 1)   // exact pow2 renorm /4
                STEP_RELOAD_F(fA4, t + 20, 0)
                STEP_RELOAD_F(fA5, t + 21, 0)
                STEP_RELOAD_F(fA6, t + 22, 0)
                STEP_RELOAD_F(fA7, t + 23, 1)
                STEP_RELOAD_F(fB0, t + 24, 0)
                STEP_RELOAD_F(fB1, t + 25, 0)
                STEP_RELOAD_F(fB2, t + 26, 0)
                STEP_RELOAD_F(fB3, t + 27, 1)
                STEP_RELOAD_F(fB4, t + 28, 0)
                STEP_RELOAD_F(fB5, t + 29, 0)
                STEP_RELOAD_F(fB6, t + 30, 0)
                STEP_RELOAD_F(fB7, t + 31, 1)
            }
            if (t + 0  < h) { STEP_NR_F(fA0, 1) }
            if (t + 1  < h) { STEP_NR_F(fA1, 1) }
            if (t + 2  < h) { STEP_NR_F(fA2, 1) }
            if (t + 3  < h) { STEP_NR_F(fA3, 1) }
            if (t + 4  < h) { STEP_NR_F(fA4, 1) }
            if (t + 5  < h) { STEP_NR_F(fA5, 1) }
            if (t + 6  < h) { STEP_NR_F(fA6, 1) }
            if (t + 7  < h) { STEP_NR_F(fA7, 1) }
            if (t + 8  < h) { STEP_NR_F(fB0, 1) }
            if (t + 9  < h) { STEP_NR_F(fB1, 1) }
            if (t + 10 < h) { STEP_NR_F(fB2, 1) }
            if (t + 11 < h) { STEP_NR_F(fB3, 1) }
            if (t + 12 < h) { STEP_NR_F(fB4, 1) }
            if (t + 13 < h) { STEP_NR_F(fB5, 1) }
            if (t + 14 < h) { STEP_NR_F(fB6, 1) }
        } else {
            // ========== backward: x = u, t = n-1 .. h, cnt = n-h ============
            // x_new[j] = sum_i (x_i * F_{t,i}) * e^trans[j][i] -> row weights
#define DECL_E2(k) f2 E2_##k = { fexp2(strans[j * NTAG + ib + 2*(k)] * LOG2E), \
                                 fexp2(strans[j * NTAG + ib + 2*(k) + 1] * LOG2E) };
            REPEAT8(DECL_E2)
#undef DECL_E2
            S = fexp2(strans[j * NTAG + STOP] * LOG2E);   // u_j
            const int cnt = n - h;
#define LDB(s_) frow[(((n - 1 - (s_)) > 0) ? (n - 1 - (s_)) : 0) * NTAG + j]
            float gA0 = LDB(0),  gA1 = LDB(1),  gA2 = LDB(2),  gA3 = LDB(3),
                  gA4 = LDB(4),  gA5 = LDB(5),  gA6 = LDB(6),  gA7 = LDB(7);
            float gB0 = LDB(8),  gB1 = LDB(9),  gB2 = LDB(10), gB3 = LDB(11),
                  gB4 = LDB(12), gB5 = LDB(13), gB6 = LDB(14), gB7 = LDB(15);
#undef LDB
            int s = 0;
            for (; s + 16 <= cnt; s += 16) {
                PIN_E2
                STEP_RELOAD_B(gA0, n - 1 - (s + 0)  - 16, 0)
                STEP_RELOAD_B(gA1, n - 1 - (s + 1)  - 16, 0)
                STEP_RELOAD_B(gA2, n - 1 - (s + 2)  - 16, 0)
                STEP_RELOAD_B(gA3, n - 1 - (s + 3)  - 16, 1)
                STEP_RELOAD_B(gA4, n - 1 - (s + 4)  - 16, 0)
                STEP_RELOAD_B(gA5, n - 1 - (s + 5)  - 16, 0)
                STEP_RELOAD_B(gA6, n - 1 - (s + 6)  - 16, 0)
                STEP_RELOAD_B(gA7, n - 1 - (s + 7)  - 16, 1)
                STEP_RELOAD_B(gB0, n - 1 - (s + 8)  - 16, 0)
                STEP_RELOAD_B(gB1, n - 1 - (s + 9)  - 16, 0)
                STEP_RELOAD_B(gB2, n - 1 - (s + 10) - 16, 0)
                STEP_RELOAD_B(gB3, n - 1 - (s + 11) - 16, 1)
                STEP_RELOAD_B(gB4, n - 1 - (s + 12) - 16, 0)
                STEP_RELOAD_B(gB5, n - 1 - (s + 13) - 16, 0)
                STEP_RELOAD_B(gB6, n - 1 - (s + 14) - 16, 0)
                STEP_RELOAD_B(gB7, n - 1 - (s + 15) - 16, 1)
            }
            if (s + 0  < cnt) { STEP_NR_B(gA0, 1) }
            if (s + 1  < cnt) { STEP_NR_B(gA1, 1) }
            if (s + 2  < cnt) { STEP_NR_B(gA2, 1) }
            if (s + 3  < cnt) { STEP_NR_B(gA3, 1) }
            if (s + 4  < cnt) { STEP_NR_B(gA4, 1) }
            if (s + 5  < cnt) { STEP_NR_B(gA5, 1) }
            if (s + 6  < cnt) { STEP_NR_B(gA6, 1) }
            if (s + 7  < cnt) { STEP_NR_B(gA7, 1) }
            if (s + 8  < cnt) { STEP_NR_B(gB0, 1) }
            if (s + 9  < cnt) { STEP_NR_B(gB1, 1) }
            if (s + 10 < cnt) { STEP_NR_B(gB2, 1) }
            if (s + 11 < cnt) { STEP_NR_B(gB3, 1) }
            if (s + 12 < cnt) { STEP_NR_B(gB4, 1) }
            if (s + 13 < cnt) { STEP_NR_B(gB5, 1) }
            if (s + 14 < cnt) { STEP_NR_B(gB6, 1) }
        }
        if (!up) { sRes[wave][j] = S; sM2[wave][j] = M2i; }
    } else {
        // ================= gold waves (pure gathers) ========================
        int b = blockIdx.x * 4 + (wave - 8);
        if (b < B) {
            b = __builtin_amdgcn_readfirstlane(b);
            const int n = wsl[b];
            const float* __restrict__ frow = feats + (size_t)b * L * NTAG;
            const int*   __restrict__ trow = tags  + (size_t)b * L;
            float acc = 0.f;
            for (int tt = lane; tt < L; tt += 64) {
                const int tg = trow[tt];
                if (tt == 0) {
                    acc += strans[START * NTAG + tg] + frow[tg];
                } else if (tt < n) {
                    const int tgp = trow[tt - 1];
                    acc += strans[tgp * NTAG + tg] + frow[tt * NTAG + tg];
                }
                if (tt == n - 1) {
                    acc += strans[tg * NTAG + STOP];
                }
            }
#pragma unroll
            for (int k = 1; k < 64; k <<= 1) acc += __shfl_xor(acc, k, 64);
            if (lane == 0) atomicAdd(out, -acc);
        }
    }

    __syncthreads();

    // ==== combine: score = ln2*(Mmax + log2 sum_j Sf_j*Sb_j*2^(M2_j-Mmax)) ==
    if (wave < 4) {
        const int b2 = blockIdx.x * 4 + wave;
        if (b2 < B && lane < 32) {
            const int M2s = sM2[wave][lane] + sM2[wave + 4][lane];
            const float pr = sRes[wave][lane] * sRes[wave + 4][lane];
            int mx = M2s;
#pragma unroll
            for (int k = 1; k < 32; k <<= 1) {
                const int o = __shfl_xor(mx, k, 32);
                mx = o > mx ? o : mx;
            }
            float ex = ldexpf(pr, M2s - mx);
#pragma unroll
            for (int k = 1; k < 32; k <<= 1) ex += __shfl_xor(ex, k, 32);
            if (lane == 0)
                atomicAdd(out, LN2 * ((float)mx + flog2(ex)));
        }
    }
}

extern "C" void kernel_launch(void* const* d_in, const int* in_sizes, int n_in,
                              void* d_out, int out_size, void* d_ws, size_t ws_size,
                              hipStream_t stream) {
    const float* feats = (const float*)d_in[0];
    const float* trans = (const float*)d_in[1];
    const int*   tags  = (const int*)d_in[2];
    const int*   wsl   = (const int*)d_in[3];
    float* out = (float*)d_out;

    const int B = in_sizes[3];              // word_seq_lens: (B,)
    const int L = in_sizes[2] / B;          // tags: (B, L)

    (void)hipMemsetAsync(out, 0, sizeof(float), stream);
    const int grid = (B + 3) / 4;
    crf_nll_kernel<<<grid, 768, 0, stream>>>(feats, trans, tags, wsl, out, B, L);
}

// Round 8
// 127.638 us; speedup vs baseline: 1.6147x; 1.0173x over previous
//
#include <hip/hip_runtime.h>

#define NTAG 32
#define START 30
#define STOP 31
#define LOG2E 1.44269504088896340736f
#define LN2 0.69314718055994530942f

typedef float f2 __attribute__((ext_vector_type(2)));
typedef float f4 __attribute__((ext_vector_type(4)));

__device__ __forceinline__ float fexp2(float x) {
#if __has_builtin(__builtin_amdgcn_exp2f)
    return __builtin_amdgcn_exp2f(x);   // v_exp_f32: 2^x
#else
    return exp2f(x);
#endif
}
__device__ __forceinline__ float flog2(float x) {
#if __has_builtin(__builtin_amdgcn_logf)
    return __builtin_amdgcn_logf(x);    // v_log_f32: log2(x)
#else
    return log2f(x);
#endif
}

// Half-exchange between a and b (v_permlane32_swap_b32).  VALU pipe - no DS
// latency.  With a == b == p on entry, afterwards {a, b} hold {own, other}
// in SOME order in every lane, so a + b == own + other either way.
__device__ __forceinline__ void plswap(float &a, float &b) {
#if __has_builtin(__builtin_amdgcn_permlane32_swap)
    auto r = __builtin_amdgcn_permlane32_swap(__float_as_int(a), __float_as_int(b),
                                              false, false);
    a = __int_as_float(r[0]);
    b = __int_as_float(r[1]);
#else
    asm volatile("v_permlane32_swap_b32 %0, %1" : "+v"(a), "+v"(b));
#endif
}

// packed 2xf32 math (VOP3P)
#define PKMUL(d, s, e) asm("v_pk_mul_f32 %0, %1, %2" : "=v"(d) : "v"(s), "v"(e))
#define PKFMA(d, s, e) asm("v_pk_fma_f32 %0, %1, %2, %0" : "+v"(d) : "v"(s), "v"(e))
#define PKADD(d, x, y) asm("v_pk_add_f32 %0, %1, %2" : "=v"(d) : "v"(x), "v"(y))

#define REPEAT8(M) M(0) M(1) M(2) M(3) M(4) M(5) M(6) M(7)

// One LINEAR-domain step, dot product SPLIT across wave halves:
// lanes j and j+32 both own output j; lane j handles input terms 0..15,
// lane j+32 terms 16..31 (ib = 0 / 16).  Broadcast: lower lanes write the
// 32 state values to LDS; each half reads back only ITS 16 inputs
// (4x ds_read_b128).  Cross-half combine via permlane32_swap (VALU).
// PRE=0 fwd: S <- (M^T S)*F;  PRE=1 bwd: S <- M(S*F).
// RN: WAVE-UNIFORM exact pow2 renorm - k from readfirstlane(S) (replica
// pair bitwise identical; all lanes same batch).  Per-lane k is WRONG:
// the next matvec needs all 32 states at a common scale (R7 regression).
#define STEP_CORE(fraw_, PRE, RN) { \
    const float F_ = fexp2((fraw_) * LOG2E); \
    const float y_ = (PRE) ? (S * F_) : S; \
    *swr = y_; \
    asm volatile("" ::: "memory"); \
    const f4 Q0 = srd4[0], Q1 = srd4[1], Q2 = srd4[2], Q3 = srd4[3]; \
    const f2 s0 = __builtin_shufflevector(Q0, Q0, 0, 1), s1 = __builtin_shufflevector(Q0, Q0, 2, 3); \
    const f2 s2 = __builtin_shufflevector(Q1, Q1, 0, 1), s3 = __builtin_shufflevector(Q1, Q1, 2, 3); \
    const f2 s4 = __builtin_shufflevector(Q2, Q2, 0, 1), s5 = __builtin_shufflevector(Q2, Q2, 2, 3); \
    const f2 s6 = __builtin_shufflevector(Q3, Q3, 0, 1), s7 = __builtin_shufflevector(Q3, Q3, 2, 3); \
    f2 a0, a1, a2, a3; \
    PKMUL(a0, s0, E2_0); PKMUL(a1, s1, E2_1); PKMUL(a2, s2, E2_2); PKMUL(a3, s3, E2_3); \
    PKFMA(a0, s4, E2_4); PKFMA(a1, s5, E2_5); PKFMA(a2, s6, E2_6); PKFMA(a3, s7, E2_7); \
    f2 t01, t23, tt; \
    PKADD(t01, a0, a1); PKADD(t23, a2, a3); PKADD(tt, t01, t23); \
    const float part_ = tt.x + tt.y; \
    float px_ = part_, py_ = part_; \
    plswap(px_, py_); \
    const float r_ = px_ + py_; \
    S = (PRE) ? r_ : (r_ * F_); \
    if (RN) { \
        const int b0_ = __builtin_amdgcn_readfirstlane(__float_as_int(S)); \
        const int k_ = ((b0_ >> 23) & 0xff) - 127; \
        S = __int_as_float(__float_as_int(S) - (k_ << 23)); \
        M2i += k_; } }

// forward: consume FS, reload with time index tload (16 steps ahead, clamped up)
#define STEP_RELOAD_F(FS, tload, RN) { const float fraw_ = FS; \
    { const int tc_ = ((tload) < L - 1) ? (tload) : (L - 1); \
      FS = frow[tc_ * NTAG + j]; } \
    STEP_CORE(fraw_, 0, RN) }
// backward: consume FS, reload with time index tload (16 steps behind, clamped at 0)
#define STEP_RELOAD_B(FS, tload, RN) { const float fraw_ = FS; \
    { const int tc_ = ((tload) > 0) ? (tload) : 0; \
      FS = frow[tc_ * NTAG + j]; } \
    STEP_CORE(fraw_, 1, RN) }

#define STEP_NR_F(FS, RN) { const float fraw_ = FS; STEP_CORE(fraw_, 0, RN) }
#define STEP_NR_B(FS, RN) { const float fraw_ = FS; STEP_CORE(fraw_, 1, RN) }

// zero-instruction insurance against E2 remat/spill
#define PIN_E2 \
    asm volatile("" : "+v"(E2_0), "+v"(E2_1), "+v"(E2_2), "+v"(E2_3), \
                      "+v"(E2_4), "+v"(E2_5), "+v"(E2_6), "+v"(E2_7));

// Block = 768 threads = 12 waves, grid = B/4 = 256 blocks = 1 block/CU.
// Waves 0-3: FORWARD half-chains (batch blk*4+w), all 64 lanes active
//            (split-dot).  Waves 4-7: BACKWARD half-chains.  Waves 8-11: gold.
// Wave i -> SIMD i&3: each SIMD carries one fwd + one bwd chain wave whose
// DS waits mutually hide (R6-proven), at ~54 instr/step-pair.
__global__ __launch_bounds__(768, 1) void crf_nll_kernel(
    const float* __restrict__ feats,   // B x L x 32
    const float* __restrict__ trans,   // 32 x 32
    const int*   __restrict__ tags,    // B x L
    const int*   __restrict__ wsl,     // B
    float* __restrict__ out, int B, int L)
{
    __shared__ float strans[NTAG * NTAG];
    __shared__ __align__(16) float sBC[8][104]; // [wave]: state [0..31], dummy [68..99]
    __shared__ float sRes[8][NTAG];    // fwd S (0-3), bwd x (4-7)
    __shared__ int   sM2[8];           // per-wave renorm exponent (uniform)
    for (int i = threadIdx.x; i < NTAG * NTAG; i += 768) strans[i] = trans[i];
    __syncthreads();

    const int wave = threadIdx.x >> 6;
    const int lane = threadIdx.x & 63;

    if (wave < 8) {
        const int dir = wave >> 2;            // 0 = fwd, 1 = bwd
        int b = blockIdx.x * 4 + (wave & 3);
        if (b >= B) b = B - 1;
        b = __builtin_amdgcn_readfirstlane(b);
        const int j = lane & 31;
        const bool up = lane >= 32;
        const int ib = up ? 16 : 0;           // this half's input-term base
        const int n = __builtin_amdgcn_readfirstlane(wsl[b]);
        const int h = (n + 1) >> 1;           // meet point
        const float* __restrict__ frow = feats + (size_t)b * L * NTAG;

        float* const swr = &sBC[wave][(up ? 68 : 0) + j];       // write slot (dummy for upper)
        const f4* const srd4 = (const f4*)&sBC[wave][up ? 16 : 0]; // this half's 16 inputs
        float S;
        int M2i = 0;

        if (dir == 0) {
            // ========== forward: S(0) -> S(h-1), cnt = h-1 steps ============
            // E2_k = e^trans[ib+2k..ib+2k+1][j] (columns of M for output j)
#define DECL_E2(k) f2 E2_##k = { fexp2(strans[(ib + 2*(k)) * NTAG + j] * LOG2E), \
                                 fexp2(strans[(ib + 2*(k) + 1) * NTAG + j] * LOG2E) };
            REPEAT8(DECL_E2)
#undef DECL_E2
            S = fexp2((strans[START * NTAG + j] + frow[j]) * LOG2E);
#define LDF(t_) frow[(((t_) < L - 1) ? (t_) : (L - 1)) * NTAG + j]
            float fA0 = LDF(1),  fA1 = LDF(2),  fA2 = LDF(3),  fA3 = LDF(4),
                  fA4 = LDF(5),  fA5 = LDF(6),  fA6 = LDF(7),  fA7 = LDF(8);
            float fB0 = LDF(9),  fB1 = LDF(10), fB2 = LDF(11), fB3 = LDF(12),
                  fB4 = LDF(13), fB5 = LDF(14), fB6 = LDF(15), fB7 = LDF(16);
#undef LDF
            int t = 1;
            for (; t + 16 <= h; t += 16) {
                PIN_E2
                STEP_RELOAD_F(fA0, t + 16, 0)
                STEP_RELOAD_F(fA1, t + 17, 0)
                STEP_RELOAD_F(fA2, t + 18, 0)
                STEP_RELOAD_F(fA3, t + 19, 1)   // exact pow2 renorm /4
                STEP_RELOAD_F(fA4, t + 20, 0)
                STEP_RELOAD_F(fA5, t + 21, 0)
                STEP_RELOAD_F(fA6, t + 22, 0)
                STEP_RELOAD_F(fA7, t + 23, 1)
                STEP_RELOAD_F(fB0, t + 24, 0)
                STEP_RELOAD_F(fB1, t + 25, 0)
                STEP_RELOAD_F(fB2, t + 26, 0)
                STEP_RELOAD_F(fB3, t + 27, 1)
                STEP_RELOAD_F(fB4, t + 28, 0)
                STEP_RELOAD_F(fB5, t + 29, 0)
                STEP_RELOAD_F(fB6, t + 30, 0)
                STEP_RELOAD_F(fB7, t + 31, 1)
            }
            if (t + 0  < h) { STEP_NR_F(fA0, 1) }
            if (t + 1  < h) { STEP_NR_F(fA1, 1) }
            if (t + 2  < h) { STEP_NR_F(fA2, 1) }
            if (t + 3  < h) { STEP_NR_F(fA3, 1) }
            if (t + 4  < h) { STEP_NR_F(fA4, 1) }
            if (t + 5  < h) { STEP_NR_F(fA5, 1) }
            if (t + 6  < h) { STEP_NR_F(fA6, 1) }
            if (t + 7  < h) { STEP_NR_F(fA7, 1) }
            if (t + 8  < h) { STEP_NR_F(fB0, 1) }
            if (t + 9  < h) { STEP_NR_F(fB1, 1) }
            if (t + 10 < h) { STEP_NR_F(fB2, 1) }
            if (t + 11 < h) { STEP_NR_F(fB3, 1) }
            if (t + 12 < h) { STEP_NR_F(fB4, 1) }
            if (t + 13 < h) { STEP_NR_F(fB5, 1) }
            if (t + 14 < h) { STEP_NR_F(fB6, 1) }
        } else {
            // ========== backward: x = u, t = n-1 .. h, cnt = n-h ============
            // x_new[j] = sum_i (x_i * F_{t,i}) * e^trans[j][i] -> row weights
#define DECL_E2(k) f2 E2_##k = { fexp2(strans[j * NTAG + ib + 2*(k)] * LOG2E), \
                                 fexp2(strans[j * NTAG + ib + 2*(k) + 1] * LOG2E) };
            REPEAT8(DECL_E2)
#undef DECL_E2
            S = fexp2(strans[j * NTAG + STOP] * LOG2E);   // u_j
            const int cnt = n - h;
#define LDB(s_) frow[(((n - 1 - (s_)) > 0) ? (n - 1 - (s_)) : 0) * NTAG + j]
            float gA0 = LDB(0),  gA1 = LDB(1),  gA2 = LDB(2),  gA3 = LDB(3),
                  gA4 = LDB(4),  gA5 = LDB(5),  gA6 = LDB(6),  gA7 = LDB(7);
            float gB0 = LDB(8),  gB1 = LDB(9),  gB2 = LDB(10), gB3 = LDB(11),
                  gB4 = LDB(12), gB5 = LDB(13), gB6 = LDB(14), gB7 = LDB(15);
#undef LDB
            int s = 0;
            for (; s + 16 <= cnt; s += 16) {
                PIN_E2
                STEP_RELOAD_B(gA0, n - 1 - (s + 0)  - 16, 0)
                STEP_RELOAD_B(gA1, n - 1 - (s + 1)  - 16, 0)
                STEP_RELOAD_B(gA2, n - 1 - (s + 2)  - 16, 0)
                STEP_RELOAD_B(gA3, n - 1 - (s + 3)  - 16, 1)
                STEP_RELOAD_B(gA4, n - 1 - (s + 4)  - 16, 0)
                STEP_RELOAD_B(gA5, n - 1 - (s + 5)  - 16, 0)
                STEP_RELOAD_B(gA6, n - 1 - (s + 6)  - 16, 0)
                STEP_RELOAD_B(gA7, n - 1 - (s + 7)  - 16, 1)
                STEP_RELOAD_B(gB0, n - 1 - (s + 8)  - 16, 0)
                STEP_RELOAD_B(gB1, n - 1 - (s + 9)  - 16, 0)
                STEP_RELOAD_B(gB2, n - 1 - (s + 10) - 16, 0)
                STEP_RELOAD_B(gB3, n - 1 - (s + 11) - 16, 1)
                STEP_RELOAD_B(gB4, n - 1 - (s + 12) - 16, 0)
                STEP_RELOAD_B(gB5, n - 1 - (s + 13) - 16, 0)
                STEP_RELOAD_B(gB6, n - 1 - (s + 14) - 16, 0)
                STEP_RELOAD_B(gB7, n - 1 - (s + 15) - 16, 1)
            }
            if (s + 0  < cnt) { STEP_NR_B(gA0, 1) }
            if (s + 1  < cnt) { STEP_NR_B(gA1, 1) }
            if (s + 2  < cnt) { STEP_NR_B(gA2, 1) }
            if (s + 3  < cnt) { STEP_NR_B(gA3, 1) }
            if (s + 4  < cnt) { STEP_NR_B(gA4, 1) }
            if (s + 5  < cnt) { STEP_NR_B(gA5, 1) }
            if (s + 6  < cnt) { STEP_NR_B(gA6, 1) }
            if (s + 7  < cnt) { STEP_NR_B(gA7, 1) }
            if (s + 8  < cnt) { STEP_NR_B(gB0, 1) }
            if (s + 9  < cnt) { STEP_NR_B(gB1, 1) }
            if (s + 10 < cnt) { STEP_NR_B(gB2, 1) }
            if (s + 11 < cnt) { STEP_NR_B(gB3, 1) }
            if (s + 12 < cnt) { STEP_NR_B(gB4, 1) }
            if (s + 13 < cnt) { STEP_NR_B(gB5, 1) }
            if (s + 14 < cnt) { STEP_NR_B(gB6, 1) }
        }
        if (!up) {
            sRes[wave][j] = S;
            if (j == 0) sM2[wave] = M2i;
        }
    } else {
        // ================= gold waves (pure gathers) ========================
        int b = blockIdx.x * 4 + (wave - 8);
        if (b < B) {
            b = __builtin_amdgcn_readfirstlane(b);
            const int n = wsl[b];
            const float* __restrict__ frow = feats + (size_t)b * L * NTAG;
            const int*   __restrict__ trow = tags  + (size_t)b * L;
            float acc = 0.f;
            for (int tt = lane; tt < L; tt += 64) {
                const int tg = trow[tt];
                if (tt == 0) {
                    acc += strans[START * NTAG + tg] + frow[tg];
                } else if (tt < n) {
                    const int tgp = trow[tt - 1];
                    acc += strans[tgp * NTAG + tg] + frow[tt * NTAG + tg];
                }
                if (tt == n - 1) {
                    acc += strans[tg * NTAG + STOP];
                }
            }
#pragma unroll
            for (int k = 1; k < 64; k <<= 1) acc += __shfl_xor(acc, k, 64);
            if (lane == 0) atomicAdd(out, -acc);
        }
    }

    __syncthreads();

    // ============== combine: forward score = ln2*(M2f+M2b+log2(x . S)) ======
    if (wave < 4) {
        const int b2 = blockIdx.x * 4 + wave;
        if (b2 < B && lane < 32) {
            float ex = sRes[wave][lane] * sRes[wave + 4][lane];
#pragma unroll
            for (int k = 1; k < 32; k <<= 1) ex += __shfl_xor(ex, k, 32);
            if (lane == 0)
                atomicAdd(out, LN2 * ((float)(sM2[wave] + sM2[wave + 4]) + flog2(ex)));
        }
    }
}

extern "C" void kernel_launch(void* const* d_in, const int* in_sizes, int n_in,
                              void* d_out, int out_size, void* d_ws, size_t ws_size,
                              hipStream_t stream) {
    const float* feats = (const float*)d_in[0];
    const float* trans = (const float*)d_in[1];
    const int*   tags  = (const int*)d_in[2];
    const int*   wsl   = (const int*)d_in[3];
    float* out = (float*)d_out;

    const int B = in_sizes[3];              // word_seq_lens: (B,)
    const int L = in_sizes[2] / B;          // tags: (B, L)

    (void)hipMemsetAsync(out, 0, sizeof(float), stream);
    const int grid = (B + 3) / 4;
    crf_nll_kernel<<<grid, 768, 0, stream>>>(feats, trans, tags, wsl, out, B, L);
}